// Round 8
// baseline (640.403 us; speedup 1.0000x reference)
//
#include <hip/hip_runtime.h>
#include <math.h>

#define Bn 32
#define Tn 64
#define An 6
#define Ln 32
#define Hn 128
#define FDn 256
#define Nimg (Bn*Tn)   // 2048

typedef __attribute__((ext_vector_type(8))) short frag_ab;   // 8 bf16
typedef __attribute__((ext_vector_type(4))) float frag_cd;   // 4 fp32
typedef _Float16 h2_t __attribute__((ext_vector_type(2)));

__device__ __forceinline__ float sigmoid_fast(float x){
  return __builtin_amdgcn_rcpf(1.f + __expf(-x));
}
__device__ __forceinline__ float tanh_fast(float x){
  float x2 = fminf(fmaxf(2.f*x, -30.f), 30.f);
  float e = __expf(x2);
  return (e - 1.f) * __builtin_amdgcn_rcpf(e + 1.f);
}

__device__ __forceinline__ unsigned short f2bf(float f){
  unsigned int u = __float_as_uint(f);
  unsigned int r = (u + 0x7fffu + ((u >> 16) & 1u)) >> 16;
  return (unsigned short)r;
}
__device__ __forceinline__ unsigned packh(float a, float b){
  union { h2_t h; unsigned u; } x;
  x.h = (h2_t){(_Float16)a, (_Float16)b};
  return x.u;
}
__device__ __forceinline__ float fdot2u(unsigned a, unsigned b, float c){
  union { unsigned u; h2_t h; } ua, ub;
  ua.u = a; ub.u = b;
#if __has_builtin(__builtin_amdgcn_fdot2)
  return __builtin_amdgcn_fdot2(ua.h, ub.h, c, false);
#else
  return c + (float)ua.h.x*(float)ub.h.x + (float)ua.h.y*(float)ub.h.y;
#endif
}
// barrier without vmcnt drain: global loads/stores in flight stay in flight
#define BAR_LDS() asm volatile("s_waitcnt lgkmcnt(0)\n\ts_barrier" ::: "memory")

// LDS swizzle (units: unsigned short). granule(row,p) = 16p + (row ^ 2p):
// conflict-free for writes (2-row x 4-p groups -> 8 distinct bank-sets) and
// reads (8-row x fixed-q groups -> 8 distinct bank-sets).
__device__ __forceinline__ int aswz_w(int r, int p){
  return ((r >> 4) << 9) + (p << 7) + (((r & 15) ^ (p << 1)) << 3);
}
__device__ __forceinline__ int aswz_r(int lane){
  return ((lane >> 4) << 7) + (((lane & 15) ^ ((lane >> 4) << 1)) << 3);
}

// packed fragment-major B index: element (k, kd) of a (Kout x KD) B^T matrix
// lives at ((kd>>5)*KF + (k>>4))*512 + (((kd>>3)&3)*16 + (k&15))*8 + (kd&7)

// ---------------------------------------------------------------------------
// states: (2048, 3, 64, 64) fp32 NCHW -> (2048, 64, 64, 4) bf16 NHWC (c3 = 0)
// ---------------------------------------------------------------------------
__global__ void __launch_bounds__(256)
states_nhwc_kernel(const float* __restrict__ src, unsigned short* __restrict__ dst)
{
  int idx = blockIdx.x*256 + threadIdx.x;      // 2048*4096
  int n = idx >> 12, pix = idx & 4095;
  const float* s = src + (size_t)n*3*4096 + pix;
  union { unsigned short e[4]; uint2 v; } u;
  u.e[0] = f2bf(s[0]); u.e[1] = f2bf(s[4096]); u.e[2] = f2bf(s[8192]); u.e[3] = 0;
  *(uint2*)(dst + (size_t)idx*4) = u.v;
}

// ---------------------------------------------------------------------------
// Scan weight image layout (f16 pairs, uints):
#define WHH4_U 24576
#define PO4_U  (64*53*4)        // 13568
#define SCAN_U (WHH4_U + PO4_U) // 38144 uints

// merged prep: conv/fc weights -> fragment-major bf16 + scan f16 packs
__global__ void __launch_bounds__(256)
prep2_kernel(const float* __restrict__ c1w, const float* __restrict__ c2w,
             const float* __restrict__ c3w, const float* __restrict__ c4w,
             const float* __restrict__ fcw,
             const float* __restrict__ gwhh, const float* __restrict__ gwih,
             const float* __restrict__ prw,  const float* __restrict__ pow_,
             unsigned short* __restrict__ w1p, unsigned short* __restrict__ w2p,
             unsigned short* __restrict__ w3p, unsigned short* __restrict__ w4p,
             unsigned short* __restrict__ wfcp,
             unsigned* __restrict__ g_scan, unsigned* __restrict__ g_wih2,
             unsigned* __restrict__ g_pr2)
{
  const int bid = blockIdx.x, tid = threadIdx.x;
  if (bid < 128){            // c2: Kout=64 KF=4 Cin=32 KD=512
    int idx = bid*256+tid;
    int k = idx >> 9, kd = idx & 511;
    int tap = kd >> 5, c = kd & 31;
    int dst = ((kd>>5)*4 + (k>>4))*512 + ((((kd>>3)&3)<<4) + (k&15))*8 + (kd&7);
    w2p[dst] = f2bf(c2w[k*512 + c*16 + tap]);
  } else if (bid < 640){     // c3: Kout=128 KF=8 Cin=64 KD=1024
    int idx = (bid-128)*256+tid;
    int k = idx >> 10, kd = idx & 1023;
    int tap = kd >> 6, c = kd & 63;
    int dst = ((kd>>5)*8 + (k>>4))*512 + ((((kd>>3)&3)<<4) + (k&15))*8 + (kd&7);
    w3p[dst] = f2bf(c3w[k*1024 + c*16 + tap]);
  } else if (bid < 2688){    // c4: Kout=256 KF=16 Cin=128 KD=2048
    int idx = (bid-640)*256+tid;
    int k = idx >> 11, kd = idx & 2047;
    int tap = kd >> 7, c = kd & 127;
    int dst = ((kd>>5)*16 + (k>>4))*512 + ((((kd>>3)&3)<<4) + (k&15))*8 + (kd&7);
    w4p[dst] = f2bf(c4w[k*2048 + c*16 + tap]);
  } else if (bid < 6784){    // fc: Kout=256 KF=16 KD=4096, kd = sp*256+c
    int idx = (bid-2688)*256+tid;
    int k = idx >> 12, kd = idx & 4095;
    int sp = kd >> 8, c = kd & 255;
    int dst = ((kd>>5)*16 + (k>>4))*512 + ((((kd>>3)&3)<<4) + (k&15))*8 + (kd&7);
    wfcp[dst] = f2bf(fcw[k*4096 + c*16 + sp]);
  } else if (bid < 6792){    // c1: Kout=32 KF=2 Cin=4(pad) KD=64
    int idx = (bid-6784)*256+tid;
    if (idx < 2048){
      int k = idx >> 6, kd = idx & 63;
      int tap = kd >> 2, c = kd & 3;
      int dst = ((kd>>5)*2 + (k>>4))*512 + ((((kd>>3)&3)<<4) + (k&15))*8 + (kd&7);
      w1p[dst] = (c < 3) ? f2bf(c1w[k*48 + c*16 + tap]) : (unsigned short)0;
    }
  } else if (bid < 6888){    // whh pack: 24576 uints
    int idx = (bid-6792)*256+tid;
    int q = idx & 3, r2 = idx >> 2;
    int k8 = r2 / 384, i = r2 - k8*384;
    int k = 8*k8 + 2*q;
    g_scan[idx] = packh(gwhh[i*128 + k], gwhh[i*128 + k + 1]);
  } else if (bid < 6917){    // wih pack: 7296 uints
    int idx = (bid-6888)*256+tid;
    if (idx < 19*384){
      int c = idx / 384, i = idx - c*384;
      g_wih2[idx] = packh(gwih[i*38 + 2*c], gwih[i*38 + 2*c + 1]);
    }
  } else if (bid < 6933){    // prior pack: 4096 uints
    int idx = (bid-6917)*256+tid;
    int o = idx >> 6, c = idx & 63;
    g_pr2[idx] = packh(prw[o*128 + 2*c], prw[o*128 + 2*c + 1]);
  } else {                   // post pack: 12288 entries
    int idx = (bid-6933)*256+tid;
    if (idx < 64*192){
      int o = idx / 192, r2 = idx - o*192;
      int u = r2 >> 2, q = r2 & 3;
      int j = u / 12, kk = u - j*12;
      int k = 96*j + 8*kk + 2*q;
      g_scan[WHH4_U + (o*53 + j*13 + kk)*4 + q] =
        packh(pow_[o*384 + k], pow_[o*384 + k + 1]);
    }
  }
}

// ---------------------------------------------------------------------------
// NHWC implicit-GEMM conv (k=4, s=2, p=1), MFMA 16x16x32 bf16.
// v3: A via LDS (fixed swizzle, dbuf, wave-private rows: wave w owns 32 rows);
// B direct-from-global fragment-major (register dbuf, no LDS); one lgkm-only
// barrier per chunk; global prefetch (A regs + B regs) in flight across it.
// ---------------------------------------------------------------------------
template<int Cin, int IN, int Kout, int OUT, int BN, int LOG_SPB>
__global__ void __launch_bounds__(256)
convN_mfma(const unsigned short* __restrict__ in,
           const unsigned short* __restrict__ wB2,  // packed fragment-major
           const float* __restrict__ bias,
           unsigned short* __restrict__ out)
{
  constexpr int SPB = OUT*OUT;
  constexpr int KD  = 16*Cin;
  constexpr int NCH = KD/32;
  constexpr int NFN = BN/16;      // B frags per wave (wave covers all BN)
  constexpr int KF  = Kout/16;
  __shared__ __align__(16) unsigned short Alds[2][8*512];

  const int tid = threadIdx.x;
  const int wave = tid >> 6, lane = tid & 63;
  const unsigned m0 = blockIdx.x * 128;
  const int nf0 = blockIdx.y * NFN;

  // A staging geometry: thread covers (row r=tid>>2, piece p=tid&3) and (r+64,p)
  const int p = tid & 3;
  const unsigned short* baseA[2]; int oyA[2], oxA[2]; int AdstI[2];
#pragma unroll
  for (int h = 0; h < 2; h++){
    int r = (tid >> 2) + h*64;
    unsigned m = m0 + r;
    int nimg = m >> LOG_SPB;
    int sp = m & (SPB - 1);
    oyA[h] = sp / OUT; oxA[h] = sp & (OUT - 1);
    baseA[h] = in + (size_t)nimg * IN * IN * Cin;
    AdstI[h] = aswz_w(r, p);
  }

  const unsigned short* wBl = wB2 + (size_t)nf0*512 + lane*8;
  const int rdoff = aswz_r(lane);

  frag_cd acc[2][NFN];
#pragma unroll
  for (int i = 0; i < 2; i++)
#pragma unroll
    for (int j = 0; j < NFN; j++) acc[i][j] = (frag_cd){0.f,0.f,0.f,0.f};

  auto loadA = [&](int kt, int h) -> uint4 {
    if constexpr (Cin >= 32){
      constexpr int CPT = Cin/32;
      int tap = kt / CPT;
      int c0 = (kt - tap*CPT)*32;
      int kh = tap >> 2, kw = tap & 3;
      int iy = 2*oyA[h] - 1 + kh;
      int ix = 2*oxA[h] - 1 + kw;
      uint4 v = {0u,0u,0u,0u};
      if ((unsigned)iy < (unsigned)IN && (unsigned)ix < (unsigned)IN)
        v = *(const uint4*)(baseA[h] + ((iy*IN + ix)*Cin + c0 + p*8));
      return v;
    } else {
      int kh = kt*2 + (p >> 1);
      int kw0 = (p & 1)*2;
      int iy = 2*oyA[h] - 1 + kh;
      int ix0 = 2*oxA[h] - 1 + kw0;
      union { uint2 u2[2]; uint4 u4; } v; v.u4 = (uint4){0u,0u,0u,0u};
      bool iyok = (unsigned)iy < (unsigned)IN;
      const unsigned short* rowp = baseA[h] + iy*IN*4;
#pragma unroll
      for (int d = 0; d < 2; d++){
        int ix = ix0 + d;
        if (iyok && (unsigned)ix < (unsigned)IN) v.u2[d] = *(const uint2*)(rowp + ix*4);
      }
      return v.u4;
    }
  };

  union U4F { uint4 u; frag_ab f; };
  U4F bR[2][NFN];

  // prologue: stage A chunk 0, prefetch A chunk 1 + B chunks 0/1
  uint4 aR0 = loadA(0,0), aR1 = loadA(0,1);
#pragma unroll
  for (int j = 0; j < NFN; j++) bR[0][j].u = *(const uint4*)(wBl + j*512);
  if (NCH > 1){
#pragma unroll
    for (int j = 0; j < NFN; j++) bR[1][j].u = *(const uint4*)(wBl + (KF + j)*512);
  }
  *(uint4*)&Alds[0][AdstI[0]] = aR0;
  *(uint4*)&Alds[0][AdstI[1]] = aR1;
  if (NCH > 1){ aR0 = loadA(1,0); aR1 = loadA(1,1); }
  BAR_LDS();

#pragma unroll 2
  for (int kt = 0; kt < NCH; kt++){
    const int cur = kt & 1, nxt = cur ^ 1;
    if (kt + 1 < NCH){
      *(uint4*)&Alds[nxt][AdstI[0]] = aR0;
      *(uint4*)&Alds[nxt][AdstI[1]] = aR1;
      if (kt + 2 < NCH){ aR0 = loadA(kt+2, 0); aR1 = loadA(kt+2, 1); }
    }
    frag_ab a[2];
#pragma unroll
    for (int i = 0; i < 2; i++)
      a[i] = *(const frag_ab*)&Alds[cur][(((wave<<1) + i) << 9) + rdoff];
#pragma unroll
    for (int i = 0; i < 2; i++)
#pragma unroll
      for (int j = 0; j < NFN; j++)
        acc[i][j] = __builtin_amdgcn_mfma_f32_16x16x32_bf16(a[i], bR[cur][j].f, acc[i][j], 0, 0, 0);
    if (kt + 2 < NCH){
#pragma unroll
      for (int j = 0; j < NFN; j++)
        bR[cur][j].u = *(const uint4*)(wBl + ((size_t)(kt+2)*KF + j)*512);
    }
    BAR_LDS();
  }

  // epilogue: wave w owns rows [m0+32w, m0+32w+32)
  const unsigned mbW = m0 + wave*32 + ((lane >> 4) << 2);
#pragma unroll
  for (int j = 0; j < NFN; j++){
    const int kg = (nf0 + j)*16 + (lane & 15);
    const float bv = bias[kg];
#pragma unroll
    for (int i = 0; i < 2; i++){
#pragma unroll
      for (int r4 = 0; r4 < 4; r4++){
        unsigned mg = mbW + i*16 + r4;
        out[(size_t)mg*Kout + kg] = f2bf(fmaxf(acc[i][j][r4] + bv, 0.f));
      }
    }
  }
}

// ---------------------------------------------------------------------------
// FC GEMM: A (2048 x 4096) bf16, W packed fragment-major. BM=64 (wave owns 16
// rows), BN=32, B direct-from-global, same swizzle+dbuf. Grid 32x8=256 blocks.
// ---------------------------------------------------------------------------
__global__ void __launch_bounds__(256)
fc_mfma3(const unsigned short* __restrict__ A, const unsigned short* __restrict__ wB2,
         const float* __restrict__ bias, float* __restrict__ outF)
{
  constexpr int KD = 4096, NCH = KD/32, KF = 16, NFN = 2;
  __shared__ __align__(16) unsigned short Alds[2][4*512];

  const int tid = threadIdx.x, wave = tid >> 6, lane = tid & 63;
  const int m0 = blockIdx.x * 64;
  const int nf0 = blockIdx.y * NFN;
  const int r = tid >> 2, pc = tid & 3;
  const unsigned short* Asrc = A + (size_t)(m0 + r)*KD + pc*8;
  const int wI = aswz_w(r, pc);
  const unsigned short* wBl = wB2 + (size_t)nf0*512 + lane*8;
  const int rdoff = aswz_r(lane);

  frag_cd acc[NFN];
#pragma unroll
  for (int j = 0; j < NFN; j++) acc[j] = (frag_cd){0.f,0.f,0.f,0.f};

  union U4F { uint4 u; frag_ab f; };
  U4F bR[2][NFN];

  uint4 aP = *(const uint4*)Asrc;
#pragma unroll
  for (int j = 0; j < NFN; j++) bR[0][j].u = *(const uint4*)(wBl + j*512);
#pragma unroll
  for (int j = 0; j < NFN; j++) bR[1][j].u = *(const uint4*)(wBl + (KF + j)*512);
  *(uint4*)&Alds[0][wI] = aP;
  aP = *(const uint4*)(Asrc + 32);
  BAR_LDS();

#pragma unroll 2
  for (int kt = 0; kt < NCH; kt++){
    const int cur = kt & 1, nxt = cur ^ 1;
    if (kt + 1 < NCH){
      *(uint4*)&Alds[nxt][wI] = aP;
      if (kt + 2 < NCH) aP = *(const uint4*)(Asrc + (kt+2)*32);
    }
    frag_ab a = *(const frag_ab*)&Alds[cur][(wave << 9) + rdoff];
#pragma unroll
    for (int j = 0; j < NFN; j++)
      acc[j] = __builtin_amdgcn_mfma_f32_16x16x32_bf16(a, bR[cur][j].f, acc[j], 0, 0, 0);
    if (kt + 2 < NCH){
#pragma unroll
      for (int j = 0; j < NFN; j++)
        bR[cur][j].u = *(const uint4*)(wBl + ((size_t)(kt+2)*KF + j)*512);
    }
    BAR_LDS();
  }

  const int mb = m0 + wave*16 + ((lane >> 4) << 2);
#pragma unroll
  for (int j = 0; j < NFN; j++){
    const int kg = (nf0 + j)*16 + (lane & 15);
    const float bv = bias[kg];
#pragma unroll
    for (int r4 = 0; r4 < 4; r4++)
      outF[(size_t)(mb + r4)*256 + kg] = acc[j][r4] + bv;
  }
}

// ---------------------------------------------------------------------------
// RSSM scan v4 (unchanged from R5)
// ---------------------------------------------------------------------------
__global__ void __launch_bounds__(384)
rssm_scan4(const float* __restrict__ actions, const float* __restrict__ feats,
           const float* __restrict__ eps,
           const unsigned* __restrict__ g_scan,
           const unsigned* __restrict__ g_wih2,
           const unsigned* __restrict__ g_pr2,
           const float* __restrict__ bih,  const float* __restrict__ bhh,
           const float* __restrict__ prior_b, const float* __restrict__ post_b,
           float* __restrict__ out)
{
  __shared__ __align__(16) _Float16 sh_hfh[384];
  __shared__ __align__(16) _Float16 sh_xh[40];
  __shared__ __align__(16) float sh_gi[384];
  __shared__ __align__(16) float sh_gh[384];

  const int b = blockIdx.x, tid = threadIdx.x;

  uint4 whhr[16];
  {
    const uint4* src = (const uint4*)g_scan;
#pragma unroll
    for (int k8 = 0; k8 < 16; k8++) whhr[k8] = src[k8*384 + tid];
  }
  unsigned wih[19];
#pragma unroll
  for (int c = 0; c < 19; c++) wih[c] = g_wih2[c*384 + tid];

  unsigned prw[32];
  float prb = 0.f;
  if (tid < 128){
    const unsigned* src = g_pr2 + (tid >> 1)*64 + (tid & 1)*32;
#pragma unroll
    for (int c = 0; c < 32; c++) prw[c] = src[c];
    prb = prior_b[tid >> 1];
  }

  int om = 0, pj = 0, o_p = 0; bool is_mu = false; float pob = 0.f;
  uint4 pww[12];
  if (tid >= 128){
    const int tt = tid - 128;
    om = tt >> 2; pj = tt & 3;
    o_p = (om >> 1) + (om & 1)*32;
    is_mu = !(om & 1);
    pob = post_b[o_p];
    const uint4* src = (const uint4*)(g_scan + WHH4_U) + o_p*53 + pj*13;
#pragma unroll
    for (int kk = 0; kk < 12; kk++) pww[kk] = src[kk];
  }

  const float bih_i = bih[tid], bhh_i = bhh[tid];
  float hreg = 0.f;

  {
    const int bt0 = b*Tn;
    if (tid < Hn) sh_hfh[tid] = (_Float16)0.f;
    if (tid < Ln) sh_xh[tid] = (_Float16)0.f;
    if (tid >= 32 && tid < 38) sh_xh[tid] = (_Float16)actions[(size_t)bt0*An + (tid-32)];
    if (tid >= 64 && tid < 320) sh_hfh[128 + tid - 64] = (_Float16)feats[(size_t)bt0*FDn + (tid-64)];
  }
  __syncthreads();

  const uint4* H4   = (const uint4*)sh_hfh;
  const unsigned* X2 = (const unsigned*)sh_xh;

  const int OFF_MUP = 0;
  const int OFF_LVP = Bn*Tn*Ln;
  const int OFF_MUQ = 2*Bn*Tn*Ln;
  const int OFF_LVQ = 3*Bn*Tn*Ln;
  const int OFF_H   = 4*Bn*Tn*Ln;
  const int OFF_Z   = 4*Bn*Tn*Ln + Bn*Tn*Hn;

  float freg = 0.f, areg = 0.f, epsr = 0.f;

  for (int t = 0; t < Tn; t++){
    const int bt = b*Tn + t;

    if (t > 0 && tid >= 64 && tid < 320) sh_hfh[128 + tid - 64] = (_Float16)freg;
    if (t < Tn-1){
      if (tid >= 64 && tid < 320) freg = feats[(size_t)(bt+1)*FDn + (tid-64)];
      if (tid >= 320 && tid < 326) areg = actions[(size_t)(bt+1)*An + (tid-320)];
    }
    if (tid >= 128 && ((tid-128)&7) == 0) epsr = eps[(size_t)bt*Ln + ((tid-128)>>3)];

    {
      float a0 = bih_i, a1 = 0.f;
#pragma unroll
      for (int c = 0; c < 19; c += 2) a0 = fdot2u(wih[c], X2[c], a0);
#pragma unroll
      for (int c = 1; c < 19; c += 2) a1 = fdot2u(wih[c], X2[c], a1);
      sh_gi[tid] = a0 + a1;

      float g0 = bhh_i, g1 = 0.f, g2 = 0.f, g3 = 0.f;
#pragma unroll
      for (int k8 = 0; k8 < 16; k8++){
        uint4 w = whhr[k8];
        uint4 h = H4[k8];
        g0 = fdot2u(w.x, h.x, g0);
        g1 = fdot2u(w.y, h.y, g1);
        g2 = fdot2u(w.z, h.z, g2);
        g3 = fdot2u(w.w, h.w, g3);
      }
      sh_gh[tid] = (g0 + g1) + (g2 + g3);
    }
    BAR_LDS();

    if (tid < Hn){
      const float r  = sigmoid_fast(sh_gi[tid]       + sh_gh[tid]);
      const float zg = sigmoid_fast(sh_gi[Hn  + tid] + sh_gh[Hn  + tid]);
      const float nn = tanh_fast(fmaf(r, sh_gh[2*Hn + tid], sh_gi[2*Hn + tid]));
      hreg = (1.f - zg)*nn + zg*hreg;
      sh_hfh[tid] = (_Float16)hreg;
      out[OFF_H + (size_t)bt*Hn + tid] = hreg;
    }
    if (t < Tn-1 && tid >= 320 && tid < 326) sh_xh[32 + tid - 320] = (_Float16)areg;
    BAR_LDS();

    if (tid < 128){
      const int j = tid & 1;
      float a0 = 0.f, a1 = 0.f, a2 = 0.f, a3 = 0.f;
#pragma unroll
      for (int c4 = 0; c4 < 8; c4++){
        uint4 h = H4[8*j + c4];
        a0 = fdot2u(prw[4*c4+0], h.x, a0);
        a1 = fdot2u(prw[4*c4+1], h.y, a1);
        a2 = fdot2u(prw[4*c4+2], h.z, a2);
        a3 = fdot2u(prw[4*c4+3], h.w, a3);
      }
      float p = (a0 + a1) + (a2 + a3);
      p += __shfl_xor(p, 1);
      if (j == 0){
        const int o = tid >> 1;
        p += prb;
        if (o < Ln) out[OFF_MUP + (size_t)bt*Ln + o] = p;
        else        out[OFF_LVP + (size_t)bt*Ln + (o - Ln)] = p;
      }
    } else {
      float a0 = 0.f, a1 = 0.f, a2 = 0.f, a3 = 0.f;
#pragma unroll
      for (int kk = 0; kk < 12; kk++){
        uint4 w = pww[kk];
        uint4 h = H4[pj*12 + kk];
        a0 = fdot2u(w.x, h.x, a0);
        a1 = fdot2u(w.y, h.y, a1);
        a2 = fdot2u(w.z, h.z, a2);
        a3 = fdot2u(w.w, h.w, a3);
      }
      float p = (a0 + a1) + (a2 + a3);
      p += __shfl_xor(p, 1);
      p += __shfl_xor(p, 2);
      p += pob;
      const float q_part = __shfl_xor(p, 4);
      if (pj == 0){
        if (is_mu){
          const int o = om >> 1;
          out[OFF_MUQ + (size_t)bt*Ln + o] = p;
          const float zz = fmaf(__expf(0.5f*q_part), epsr, p);
          sh_xh[o] = (_Float16)zz;
          out[OFF_Z + (size_t)bt*Ln + o] = zz;
        } else {
          out[OFF_LVQ + (size_t)bt*Ln + (o_p - Ln)] = p;
        }
      }
    }
    BAR_LDS();
  }
}

// ---------------------------------------------------------------------------
extern "C" void kernel_launch(void* const* d_in, const int* in_sizes, int n_in,
                              void* d_out, int out_size, void* d_ws, size_t ws_size,
                              hipStream_t stream)
{
  const float* states = (const float*)d_in[0];
  const float* actions= (const float*)d_in[1];
  const float* c1_w = (const float*)d_in[2];  const float* c1_b = (const float*)d_in[3];
  const float* c2_w = (const float*)d_in[4];  const float* c2_b = (const float*)d_in[5];
  const float* c3_w = (const float*)d_in[6];  const float* c3_b = (const float*)d_in[7];
  const float* c4_w = (const float*)d_in[8];  const float* c4_b = (const float*)d_in[9];
  const float* fc_w = (const float*)d_in[10]; const float* fc_b = (const float*)d_in[11];
  const float* gwih = (const float*)d_in[12]; const float* gwhh = (const float*)d_in[13];
  const float* gbih = (const float*)d_in[14]; const float* gbhh = (const float*)d_in[15];
  const float* pr_w = (const float*)d_in[16]; const float* pr_b = (const float*)d_in[17];
  const float* po_w = (const float*)d_in[18]; const float* po_b = (const float*)d_in[19];
  const float* eps  = (const float*)d_in[20];

  char* p = (char*)d_ws;
  auto alloc = [&](size_t bytes){ char* r = p; p += (bytes + 255) & ~255ULL; return r; };

  unsigned short* statesB = (unsigned short*)alloc((size_t)Nimg*4096*4*2); // NHWC c=4
  unsigned short* act1    = (unsigned short*)alloc((size_t)Nimg*1024*32*2);
  unsigned short* act2    = (unsigned short*)alloc((size_t)Nimg*256*64*2);
  unsigned short* act3    = (unsigned short*)alloc((size_t)Nimg*64*128*2);
  unsigned short* act4    = (unsigned short*)alloc((size_t)Nimg*16*256*2);
  float*          feats   = (float*)alloc((size_t)Nimg*FDn*4);
  unsigned short* w1p     = (unsigned short*)alloc(32*64*2);
  unsigned short* w2p     = (unsigned short*)alloc((size_t)64*512*2);
  unsigned short* w3p     = (unsigned short*)alloc((size_t)128*1024*2);
  unsigned short* w4p     = (unsigned short*)alloc((size_t)256*2048*2);
  unsigned short* wfcp    = (unsigned short*)alloc((size_t)256*4096*2);
  unsigned* g_scan = (unsigned*)alloc((size_t)SCAN_U*4);
  unsigned* g_wih2 = (unsigned*)alloc((size_t)19*384*4);
  unsigned* g_pr2  = (unsigned*)alloc((size_t)64*64*4);

  states_nhwc_kernel<<<Nimg*4096/256, 256, 0, stream>>>(states, statesB);
  prep2_kernel<<<6981, 256, 0, stream>>>(c1_w, c2_w, c3_w, c4_w, fc_w,
                                         gwhh, gwih, pr_w, po_w,
                                         w1p, w2p, w3p, w4p, wfcp,
                                         g_scan, g_wih2, g_pr2);

  // encoder: NHWC implicit-GEMM MFMA convs (BM=128, A-LDS swizzled dbuf, B-direct)
  convN_mfma<4,64,32,32,32,10>  <<< dim3(Nimg*1024/128, 1), 256, 0, stream >>>(statesB, w1p, c1_b, act1);
  convN_mfma<32,32,64,16,64,8>  <<< dim3(Nimg*256/128, 1), 256, 0, stream >>>(act1, w2p, c2_b, act2);
  convN_mfma<64,16,128,8,64,6>  <<< dim3(Nimg*64/128, 2), 256, 0, stream >>>(act2, w3p, c3_b, act3);
  convN_mfma<128,8,256,4,64,4>  <<< dim3(Nimg*16/128, 4), 256, 0, stream >>>(act3, w4p, c4_b, act4);

  fc_mfma3<<< dim3(Nimg/64, 8), 256, 0, stream >>>(act4, wfcp, fc_b, feats);

  rssm_scan4<<< Bn, 384, 0, stream >>>(actions, feats, eps,
                                       g_scan, g_wih2, g_pr2,
                                       gbih, gbhh, pr_b, po_b, (float*)d_out);
}